// Round 2
// baseline (1430.650 us; speedup 1.0000x reference)
//
#include <hip/hip_runtime.h>
#include <hip/hip_bf16.h>
#include <cstdint>
#include <cstddef>

#define BB 64
#define NN 512
#define MM 512
#define DD 128

static constexpr float SINK_EPS_F = 0.05f;
static constexpr int   ITERS      = 80;
static constexpr float A_CONST    = 1.0f / 512.0f;   // 1/N
static constexpr float B_CONST    = 1.0f / 512.0f;   // 1/M

__device__ __forceinline__ float bflo(unsigned u) { return __uint_as_float(u << 16); }
__device__ __forceinline__ float bfhi(unsigned u) { return __uint_as_float(u & 0xffff0000u); }

// ---------------- kernel 1: row inverse norms ----------------
__global__ __launch_bounds__(256) void norm_kernel(const float* __restrict__ src,
                                                   const float* __restrict__ tgt,
                                                   float* __restrict__ inv_ns,
                                                   float* __restrict__ inv_nt) {
    int wave = (blockIdx.x * blockDim.x + threadIdx.x) >> 6;
    int lane = threadIdx.x & 63;
    const float* row;
    float* out;
    if (wave < BB * NN) { row = src + (size_t)wave * DD; out = inv_ns + wave; }
    else                { row = tgt + (size_t)(wave - BB * NN) * DD; out = inv_nt + (wave - BB * NN); }
    float2 v = ((const float2*)row)[lane];
    float s = v.x * v.x + v.y * v.y;
    #pragma unroll
    for (int off = 32; off; off >>= 1) s += __shfl_xor(s, off, 64);
    if (lane == 0) *out = 1.0f / fmaxf(sqrtf(s), 1e-12f);
}

// ---------------- kernel 2: normalized GEMM -> cost -> W=exp(-C/eps) (bf16) ----------------
#define TS  128
#define BK  32
#define PAD 36   // floats per LDS row (32 + pad)

__global__ __launch_bounds__(256) void cost_kernel(const float* __restrict__ S,
                                                   const float* __restrict__ T,
                                                   const float* __restrict__ inv_ns,
                                                   const float* __restrict__ inv_nt,
                                                   unsigned short* __restrict__ W) {
    __shared__ float sA[TS * PAD];
    __shared__ float sB[TS * PAD];
    int bid = blockIdx.x;
    int b  = bid >> 4;
    int i0 = ((bid >> 2) & 3) * TS;
    int j0 = (bid & 3) * TS;
    int t  = threadIdx.x;
    int tx = t & 15, ty = t >> 4;

    float acc[8][8] = {};

    for (int kc = 0; kc < DD; kc += BK) {
        #pragma unroll
        for (int p = 0; p < 4; ++p) {
            int row = (t >> 3) + p * 32;
            int c4  = t & 7;
            {
                int gr = b * NN + i0 + row;
                float4 v = ((const float4*)(S + (size_t)gr * DD + kc))[c4];
                float sc = inv_ns[gr];
                v.x *= sc; v.y *= sc; v.z *= sc; v.w *= sc;
                *(float4*)&sA[row * PAD + c4 * 4] = v;
            }
            {
                int gr = b * MM + j0 + row;
                float4 v = ((const float4*)(T + (size_t)gr * DD + kc))[c4];
                float sc = inv_nt[gr];
                v.x *= sc; v.y *= sc; v.z *= sc; v.w *= sc;
                *(float4*)&sB[row * PAD + c4 * 4] = v;
            }
        }
        __syncthreads();

        #pragma unroll 2
        for (int k4 = 0; k4 < BK; k4 += 4) {
            float4 av[8], bv[8];
            #pragma unroll
            for (int r = 0; r < 8; ++r) av[r] = *(const float4*)&sA[(ty + 16 * r) * PAD + k4];
            #pragma unroll
            for (int c = 0; c < 8; ++c) bv[c] = *(const float4*)&sB[(tx + 16 * c) * PAD + k4];
            #pragma unroll
            for (int r = 0; r < 8; ++r)
                #pragma unroll
                for (int c = 0; c < 8; ++c)
                    acc[r][c] += av[r].x * bv[c].x + av[r].y * bv[c].y
                               + av[r].z * bv[c].z + av[r].w * bv[c].w;
        }
        __syncthreads();
    }

    #pragma unroll
    for (int r = 0; r < 8; ++r) {
        int gi = b * NN + i0 + ty + 16 * r;
        #pragma unroll
        for (int c = 0; c < 8; ++c) {
            int gj = j0 + tx + 16 * c;
            float cost = fmaxf(2.0f - 2.0f * acc[r][c], 0.0f);
            float wv = expf(-20.0f * cost);
            __hip_bfloat16 h = __float2bfloat16(wv);
            W[(size_t)gi * MM + gj] = *reinterpret_cast<unsigned short*>(&h);
        }
    }
}

// ---------------- kernel 3: 4-blocks-per-batch Sinkhorn with global barrier ----------------
// Group = blocks {b, b+64, b+128, b+192} (same XCD under bid%8 mapping).
// Cross-block u/v exchange via agent-scope relaxed atomics (bypass L1/L2 to
// coherence point); counter bumped with release. No acquire fence anywhere so
// W stays resident in each XCD's L2 across all phases.
__global__ __launch_bounds__(512) void sinkhorn_kernel(const unsigned short* __restrict__ W,
                                                       float* __restrict__ eu_g,
                                                       float* __restrict__ ev_g,
                                                       unsigned int* __restrict__ bar) {
    int gid = blockIdx.x;
    int b = gid & 63;          // batch
    int q = gid >> 6;          // quarter 0..3
    const unsigned short* Wb = W + (size_t)b * NN * MM;

    __shared__ float ev_pad[16 * 36];     // ev[j] at [(j>>5)*36 + (j&31)]
    __shared__ float eu_s[NN];
    __shared__ float part[32 * 132];      // phase-B partials, padded stride

    int t = threadIdx.x;
    int w = t >> 6, lane = t & 63;
    int sub = lane >> 4, l16 = lane & 15;
    int c16 = t & 15, rgrp = t >> 4;      // phase-B mapping

    if (t < 16 * 36) ev_pad[t] = 1.0f;    // log_v = 0 -> ev = 1
    __syncthreads();

    unsigned int* ctr = bar + b;

    for (int it = 0; it < ITERS; ++it) {
        // ---- phase A: rows [q*128, q*128+128): S_i = sum_j W_ij ev_j; eu_i = a/S_i ----
        float4 evv[8];
        #pragma unroll
        for (int c = 0; c < 8; ++c) evv[c] = *(const float4*)&ev_pad[l16 * 36 + c * 4];

        #pragma unroll
        for (int g = 0; g < 4; ++g) {
            int lr = g * 32 + w * 4 + sub;                       // 0..127
            const unsigned short* wrow = Wb + (size_t)(q * 128 + lr) * MM + l16 * 32;
            float acc = 0.0f;
            #pragma unroll
            for (int m = 0; m < 4; ++m) {
                uint4 u = ((const uint4*)wrow)[m];
                float4 e0 = evv[2 * m], e1 = evv[2 * m + 1];
                acc += bflo(u.x) * e0.x + bfhi(u.x) * e0.y + bflo(u.y) * e0.z + bfhi(u.y) * e0.w
                     + bflo(u.z) * e1.x + bfhi(u.z) * e1.y + bflo(u.w) * e1.z + bfhi(u.w) * e1.w;
            }
            acc += __shfl_xor(acc, 1, 64);
            acc += __shfl_xor(acc, 2, 64);
            acc += __shfl_xor(acc, 4, 64);
            acc += __shfl_xor(acc, 8, 64);
            if (l16 == 0)
                __hip_atomic_store(&eu_g[b * NN + q * 128 + lr], A_CONST / acc,
                                   __ATOMIC_RELAXED, __HIP_MEMORY_SCOPE_AGENT);
        }
        __syncthreads();   // drains stores (vmcnt 0) before the release add

        if (t == 0) {
            __hip_atomic_fetch_add(ctr, 1u, __ATOMIC_RELEASE, __HIP_MEMORY_SCOPE_AGENT);
            unsigned int target = 8u * it + 4u;
            while (__hip_atomic_load(ctr, __ATOMIC_RELAXED, __HIP_MEMORY_SCOPE_AGENT) < target) {
                __builtin_amdgcn_s_sleep(1);
            }
        }
        __syncthreads();

        // gather full eu (bypassing loads -> coherence point)
        eu_s[t] = __hip_atomic_load(&eu_g[b * NN + t], __ATOMIC_RELAXED, __HIP_MEMORY_SCOPE_AGENT);
        __syncthreads();

        // ---- phase B: cols [q*128, q*128+128): T_j = sum_i W_ij eu_i; ev_j = b/T_j ----
        const unsigned short* wcol = Wb + q * 128 + c16 * 8;
        float a0 = 0, a1 = 0, a2 = 0, a3 = 0, a4 = 0, a5 = 0, a6 = 0, a7 = 0;
        #pragma unroll 4
        for (int ii = 0; ii < 16; ++ii) {
            int i = rgrp + 32 * ii;
            uint4 u = *(const uint4*)(wcol + (size_t)i * MM);
            float ui = eu_s[i];
            a0 += bflo(u.x) * ui; a1 += bfhi(u.x) * ui;
            a2 += bflo(u.y) * ui; a3 += bfhi(u.y) * ui;
            a4 += bflo(u.z) * ui; a5 += bfhi(u.z) * ui;
            a6 += bflo(u.w) * ui; a7 += bfhi(u.w) * ui;
        }
        float4 p0 = {a0, a1, a2, a3}, p1 = {a4, a5, a6, a7};
        *(float4*)&part[rgrp * 132 + c16 * 8]     = p0;
        *(float4*)&part[rgrp * 132 + c16 * 8 + 4] = p1;
        __syncthreads();

        if (t < 128) {
            float s = 0.0f;
            #pragma unroll
            for (int r = 0; r < 32; ++r) s += part[r * 132 + t];
            __hip_atomic_store(&ev_g[b * MM + q * 128 + t], B_CONST / s,
                               __ATOMIC_RELAXED, __HIP_MEMORY_SCOPE_AGENT);
        }
        __syncthreads();

        if (t == 0) {
            __hip_atomic_fetch_add(ctr, 1u, __ATOMIC_RELEASE, __HIP_MEMORY_SCOPE_AGENT);
            unsigned int target = 8u * it + 8u;
            while (__hip_atomic_load(ctr, __ATOMIC_RELAXED, __HIP_MEMORY_SCOPE_AGENT) < target) {
                __builtin_amdgcn_s_sleep(1);
            }
        }
        __syncthreads();

        // gather full ev into padded LDS
        {
            float v = __hip_atomic_load(&ev_g[b * MM + t], __ATOMIC_RELAXED, __HIP_MEMORY_SCOPE_AGENT);
            ev_pad[(t >> 5) * 36 + (t & 31)] = v;
        }
        __syncthreads();
    }
    // eu_g / ev_g hold the final scalings; nothing else to write.
}

// ---------------- kernel 4: partial distances, 4 blocks per batch ----------------
__global__ __launch_bounds__(256) void dist_kernel(const unsigned short* __restrict__ W,
                                                   const float* __restrict__ eu_g,
                                                   const float* __restrict__ ev_g,
                                                   float* __restrict__ dist4) {
    int gid = blockIdx.x;
    int b = gid & 63, q = gid >> 6;
    __shared__ float eu[NN], ev[MM];
    __shared__ float red[4];
    int t = threadIdx.x;
    for (int i = t; i < NN; i += 256) eu[i] = eu_g[b * NN + i];
    for (int j = t; j < MM; j += 256) ev[j] = ev_g[b * MM + j];
    __syncthreads();

    const unsigned short* Wb = W + (size_t)b * NN * MM;
    float acc = 0.0f;
    #pragma unroll 2
    for (int s = q * 32; s < q * 32 + 32; ++s) {
        int flat = s * 256 + t;
        int i = flat >> 6, jg = flat & 63;
        uint4 u = ((const uint4*)(Wb + (size_t)i * MM))[jg];
        float4 e0 = *(const float4*)&ev[jg * 8];
        float4 e1 = *(const float4*)&ev[jg * 8 + 4];
        float w0 = bflo(u.x), w1 = bfhi(u.x), w2 = bflo(u.y), w3 = bfhi(u.y);
        float w4 = bflo(u.z), w5 = bfhi(u.z), w6 = bflo(u.w), w7 = bfhi(u.w);
        float ssum = w0 * __logf(w0) * e0.x + w1 * __logf(w1) * e0.y
                   + w2 * __logf(w2) * e0.z + w3 * __logf(w3) * e0.w
                   + w4 * __logf(w4) * e1.x + w5 * __logf(w5) * e1.y
                   + w6 * __logf(w6) * e1.z + w7 * __logf(w7) * e1.w;
        acc += eu[i] * ssum;
    }
    #pragma unroll
    for (int off = 32; off; off >>= 1) acc += __shfl_xor(acc, off, 64);
    if ((t & 63) == 0) red[t >> 6] = acc;
    __syncthreads();
    if (t == 0) dist4[gid] = red[0] + red[1] + red[2] + red[3];
}

// ---------------- kernel 5: mean over 256 partials ----------------
__global__ __launch_bounds__(256) void mean_kernel(const float* __restrict__ dist4,
                                                   float* __restrict__ out) {
    __shared__ float red[4];
    int t = threadIdx.x;
    float v = dist4[t];
    #pragma unroll
    for (int off = 32; off; off >>= 1) v += __shfl_xor(v, off, 64);
    if ((t & 63) == 0) red[t >> 6] = v;
    __syncthreads();
    if (t == 0) out[0] = -SINK_EPS_F * (red[0] + red[1] + red[2] + red[3]) * (1.0f / 64.0f);
}

extern "C" void kernel_launch(void* const* d_in, const int* in_sizes, int n_in,
                              void* d_out, int out_size, void* d_ws, size_t ws_size,
                              hipStream_t stream) {
    const float* src = (const float*)d_in[0];
    const float* tgt = (const float*)d_in[1];
    char* ws = (char*)d_ws;

    float*          inv_ns = (float*)(ws);
    float*          inv_nt = (float*)(ws + 131072);
    unsigned short* W      = (unsigned short*)(ws + 262144);
    float*          eu_g   = (float*)(ws + 262144 + 33554432);
    float*          ev_g   = (float*)(ws + 262144 + 33554432 + 131072);
    float*          dist4  = (float*)(ws + 262144 + 33554432 + 262144);
    unsigned int*   bar    = (unsigned int*)(ws + 262144 + 33554432 + 262144 + 4096);
    float*          out    = (float*)d_out;

    hipMemsetAsync(bar, 0, 64 * sizeof(unsigned int), stream);

    hipLaunchKernelGGL(norm_kernel,     dim3(16384), dim3(256), 0, stream, src, tgt, inv_ns, inv_nt);
    hipLaunchKernelGGL(cost_kernel,     dim3(1024),  dim3(256), 0, stream, src, tgt, inv_ns, inv_nt, W);
    hipLaunchKernelGGL(sinkhorn_kernel, dim3(256),   dim3(512), 0, stream, W, eu_g, ev_g, bar);
    hipLaunchKernelGGL(dist_kernel,     dim3(256),   dim3(256), 0, stream, W, eu_g, ev_g, dist4);
    hipLaunchKernelGGL(mean_kernel,     dim3(1),     dim3(256), 0, stream, dist4, out);
}

// Round 3
// 754.392 us; speedup vs baseline: 1.8964x; 1.8964x over previous
//
#include <hip/hip_runtime.h>
#include <hip/hip_bf16.h>
#include <cstdint>
#include <cstddef>

#define BB 64
#define NN 512
#define MM 512
#define DD 128

static constexpr float SINK_EPS_F = 0.05f;
static constexpr int   ITERS      = 80;
static constexpr float A_CONST    = 1.0f / 512.0f;   // 1/N
static constexpr float B_CONST    = 1.0f / 512.0f;   // 1/M

__device__ __forceinline__ float bflo(unsigned u) { return __uint_as_float(u << 16); }
__device__ __forceinline__ float bfhi(unsigned u) { return __uint_as_float(u & 0xffff0000u); }

// 2 bf16 MACs in one instruction: c += a.lo*b.lo + a.hi*b.hi
__device__ __forceinline__ float fdot2bf(unsigned a, unsigned b, float c) {
    asm("v_dot2_f32_bf16 %0, %1, %2, %0" : "+v"(c) : "v"(a), "v"(b));
    return c;
}
__device__ __forceinline__ unsigned pack2(float lo, float hi) {
    __hip_bfloat16 l = __float2bfloat16(lo), h = __float2bfloat16(hi);
    return (unsigned)*reinterpret_cast<unsigned short*>(&l)
         | ((unsigned)*reinterpret_cast<unsigned short*>(&h) << 16);
}

// ---------------- kernel 1: row inverse norms ----------------
__global__ __launch_bounds__(256) void norm_kernel(const float* __restrict__ src,
                                                   const float* __restrict__ tgt,
                                                   float* __restrict__ inv_ns,
                                                   float* __restrict__ inv_nt) {
    int wave = (blockIdx.x * blockDim.x + threadIdx.x) >> 6;
    int lane = threadIdx.x & 63;
    const float* row;
    float* out;
    if (wave < BB * NN) { row = src + (size_t)wave * DD; out = inv_ns + wave; }
    else                { row = tgt + (size_t)(wave - BB * NN) * DD; out = inv_nt + (wave - BB * NN); }
    float2 v = ((const float2*)row)[lane];
    float s = v.x * v.x + v.y * v.y;
    #pragma unroll
    for (int off = 32; off; off >>= 1) s += __shfl_xor(s, off, 64);
    if (lane == 0) *out = 1.0f / fmaxf(sqrtf(s), 1e-12f);
}

// ---------------- kernel 2: normalized GEMM -> cost -> W=exp(-C/eps) (bf16) ----------------
#define TS  128
#define BK  32
#define PAD 36

__global__ __launch_bounds__(256) void cost_kernel(const float* __restrict__ S,
                                                   const float* __restrict__ T,
                                                   const float* __restrict__ inv_ns,
                                                   const float* __restrict__ inv_nt,
                                                   unsigned short* __restrict__ W) {
    __shared__ float sA[TS * PAD];
    __shared__ float sB[TS * PAD];
    int bid = blockIdx.x;
    int b  = bid >> 4;
    int i0 = ((bid >> 2) & 3) * TS;
    int j0 = (bid & 3) * TS;
    int t  = threadIdx.x;
    int tx = t & 15, ty = t >> 4;

    float acc[8][8] = {};

    for (int kc = 0; kc < DD; kc += BK) {
        #pragma unroll
        for (int p = 0; p < 4; ++p) {
            int row = (t >> 3) + p * 32;
            int c4  = t & 7;
            {
                int gr = b * NN + i0 + row;
                float4 v = ((const float4*)(S + (size_t)gr * DD + kc))[c4];
                float sc = inv_ns[gr];
                v.x *= sc; v.y *= sc; v.z *= sc; v.w *= sc;
                *(float4*)&sA[row * PAD + c4 * 4] = v;
            }
            {
                int gr = b * MM + j0 + row;
                float4 v = ((const float4*)(T + (size_t)gr * DD + kc))[c4];
                float sc = inv_nt[gr];
                v.x *= sc; v.y *= sc; v.z *= sc; v.w *= sc;
                *(float4*)&sB[row * PAD + c4 * 4] = v;
            }
        }
        __syncthreads();

        #pragma unroll 2
        for (int k4 = 0; k4 < BK; k4 += 4) {
            float4 av[8], bv[8];
            #pragma unroll
            for (int r = 0; r < 8; ++r) av[r] = *(const float4*)&sA[(ty + 16 * r) * PAD + k4];
            #pragma unroll
            for (int c = 0; c < 8; ++c) bv[c] = *(const float4*)&sB[(tx + 16 * c) * PAD + k4];
            #pragma unroll
            for (int r = 0; r < 8; ++r)
                #pragma unroll
                for (int c = 0; c < 8; ++c)
                    acc[r][c] += av[r].x * bv[c].x + av[r].y * bv[c].y
                               + av[r].z * bv[c].z + av[r].w * bv[c].w;
        }
        __syncthreads();
    }

    #pragma unroll
    for (int r = 0; r < 8; ++r) {
        int gi = b * NN + i0 + ty + 16 * r;
        #pragma unroll
        for (int c = 0; c < 8; ++c) {
            int gj = j0 + tx + 16 * c;
            float cost = fmaxf(2.0f - 2.0f * acc[r][c], 0.0f);
            float wv = expf(-20.0f * cost);
            __hip_bfloat16 h = __float2bfloat16(wv);
            W[(size_t)gi * MM + gj] = *reinterpret_cast<unsigned short*>(&h);
        }
    }
}

// ---------------- kernel 3: column-slab Sinkhorn, ONE barrier/iter, fused distance ----
// Block (b,q) owns W[b][:, 128q:128q+128].  Per iteration:
//   phase A: partial row sums over own cols -> Sp[buf][b][q][.] (UC stores)
//   one relaxed counter barrier
//   gather 4 partials -> full eu (redundantly per block)
//   phase B: T_j for own cols (needs only eu) -> ev local, never communicated.
// Sp is double-buffered on it&1 so a fast block can't overwrite live data.
__global__ __launch_bounds__(1024) void sinkhorn_kernel(const unsigned short* __restrict__ W,
                                                        float* __restrict__ Sp,
                                                        unsigned int* __restrict__ bar,
                                                        float* __restrict__ dist4) {
    int gid = blockIdx.x;
    int b = gid & 63, q = gid >> 6;
    const unsigned short* slab = W + (size_t)b * NN * MM + q * 128;

    __shared__ float    eu_s[NN];
    __shared__ float    s_row[NN];
    __shared__ unsigned eu_pk[NN / 2];
    __shared__ unsigned ev_pk[64];
    __shared__ float    ev_f[128];
    __shared__ float    part[64 * 132];
    __shared__ float    red[16];

    int t = threadIdx.x;
    int w = t >> 6, lane = t & 63, sub = lane >> 4, l16 = lane & 15;
    int c16 = t & 15, rgrp = t >> 4;

    if (t < 64)  ev_pk[t] = 0x3F803F80u;   // (1.0bf16, 1.0bf16)
    if (t < 128) ev_f[t] = 1.0f;
    __syncthreads();

    unsigned int* ctr = bar + b;

    for (int it = 0; it < ITERS; ++it) {
        float* spbase = Sp + (size_t)(it & 1) * (BB * 4 * NN);

        // ---- phase A: partial row sums over own 128 cols ----
        uint4 evv = *(uint4*)&ev_pk[l16 * 4];
        #pragma unroll
        for (int sw = 0; sw < 8; ++sw) {
            int row = sw * 64 + w * 4 + sub;
            uint4 u = *(const uint4*)(slab + (size_t)row * MM + l16 * 8);
            float acc = 0.0f;
            acc = fdot2bf(u.x, evv.x, acc);
            acc = fdot2bf(u.y, evv.y, acc);
            acc = fdot2bf(u.z, evv.z, acc);
            acc = fdot2bf(u.w, evv.w, acc);
            acc += __shfl_xor(acc, 1, 64);
            acc += __shfl_xor(acc, 2, 64);
            acc += __shfl_xor(acc, 4, 64);
            acc += __shfl_xor(acc, 8, 64);
            if (l16 == 0) s_row[row] = acc;
        }
        __syncthreads();
        if (t < NN)
            __hip_atomic_store(&spbase[((size_t)b * 4 + q) * NN + t], s_row[t],
                               __ATOMIC_RELAXED, __HIP_MEMORY_SCOPE_AGENT);
        __syncthreads();   // drains vmcnt(0): partials at coherence point before the add

        if (t == 0) {
            __hip_atomic_fetch_add(ctr, 1u, __ATOMIC_RELAXED, __HIP_MEMORY_SCOPE_AGENT);
            unsigned tgt = 4u * (unsigned)(it + 1);
            while (__hip_atomic_load(ctr, __ATOMIC_RELAXED, __HIP_MEMORY_SCOPE_AGENT) < tgt)
                __builtin_amdgcn_s_sleep(1);
        }
        __syncthreads();

        // ---- gather 4 partials -> eu (all blocks redundantly) ----
        if (t < NN) {
            const float* g = spbase + (size_t)b * 4 * NN + t;
            float S = __hip_atomic_load(g,            __ATOMIC_RELAXED, __HIP_MEMORY_SCOPE_AGENT)
                    + __hip_atomic_load(g + NN,       __ATOMIC_RELAXED, __HIP_MEMORY_SCOPE_AGENT)
                    + __hip_atomic_load(g + 2 * NN,   __ATOMIC_RELAXED, __HIP_MEMORY_SCOPE_AGENT)
                    + __hip_atomic_load(g + 3 * NN,   __ATOMIC_RELAXED, __HIP_MEMORY_SCOPE_AGENT);
            eu_s[t] = A_CONST / S;
        }
        __syncthreads();
        if (t < NN / 2) eu_pk[t] = pack2(eu_s[2 * t], eu_s[2 * t + 1]);
        __syncthreads();

        // ---- phase B: T_j over own cols; ev local ----
        float a0 = 0, a1 = 0, a2 = 0, a3 = 0, a4 = 0, a5 = 0, a6 = 0, a7 = 0;
        const unsigned short* colbase = slab + c16 * 8;
        #pragma unroll
        for (int pp = 0; pp < 4; ++pp) {
            int p = rgrp + 64 * pp;                       // row-pair index 0..255
            const unsigned short* r0 = colbase + (size_t)(2 * p) * MM;
            uint4 u  = *(const uint4*)(r0);
            uint4 u2 = *(const uint4*)(r0 + MM);
            unsigned ep = eu_pk[p];
            a0 = fdot2bf(__builtin_amdgcn_perm(u2.x, u.x, 0x05040100u), ep, a0);
            a1 = fdot2bf(__builtin_amdgcn_perm(u2.x, u.x, 0x07060302u), ep, a1);
            a2 = fdot2bf(__builtin_amdgcn_perm(u2.y, u.y, 0x05040100u), ep, a2);
            a3 = fdot2bf(__builtin_amdgcn_perm(u2.y, u.y, 0x07060302u), ep, a3);
            a4 = fdot2bf(__builtin_amdgcn_perm(u2.z, u.z, 0x05040100u), ep, a4);
            a5 = fdot2bf(__builtin_amdgcn_perm(u2.z, u.z, 0x07060302u), ep, a5);
            a6 = fdot2bf(__builtin_amdgcn_perm(u2.w, u.w, 0x05040100u), ep, a6);
            a7 = fdot2bf(__builtin_amdgcn_perm(u2.w, u.w, 0x07060302u), ep, a7);
        }
        *(float4*)&part[rgrp * 132 + c16 * 8]     = make_float4(a0, a1, a2, a3);
        *(float4*)&part[rgrp * 132 + c16 * 8 + 4] = make_float4(a4, a5, a6, a7);
        __syncthreads();
        if (t < 128) {
            float s = 0.0f;
            #pragma unroll
            for (int r = 0; r < 64; ++r) s += part[r * 132 + t];
            ev_f[t] = B_CONST / s;
        }
        __syncthreads();
        if (t < 64) ev_pk[t] = pack2(ev_f[2 * t], ev_f[2 * t + 1]);
        __syncthreads();
    }

    // ---- fused distance partial over own cols ----
    float evr[8];
    #pragma unroll
    for (int k = 0; k < 8; ++k) evr[k] = ev_f[l16 * 8 + k];
    float dacc = 0.0f;
    #pragma unroll 2
    for (int sw = 0; sw < 8; ++sw) {
        int row = sw * 64 + w * 4 + sub;
        uint4 u = *(const uint4*)(slab + (size_t)row * MM + l16 * 8);
        float eu = eu_s[row];
        float w0 = bflo(u.x), w1 = bfhi(u.x), w2 = bflo(u.y), w3 = bfhi(u.y);
        float w4 = bflo(u.z), w5 = bfhi(u.z), w6 = bflo(u.w), w7 = bfhi(u.w);
        float s = w0 * __logf(w0) * evr[0] + w1 * __logf(w1) * evr[1]
                + w2 * __logf(w2) * evr[2] + w3 * __logf(w3) * evr[3]
                + w4 * __logf(w4) * evr[4] + w5 * __logf(w5) * evr[5]
                + w6 * __logf(w6) * evr[6] + w7 * __logf(w7) * evr[7];
        dacc += eu * s;
    }
    #pragma unroll
    for (int off = 32; off; off >>= 1) dacc += __shfl_xor(dacc, off, 64);
    if (lane == 0) red[w] = dacc;
    __syncthreads();
    if (t == 0) {
        float s = 0.0f;
        #pragma unroll
        for (int i = 0; i < 16; ++i) s += red[i];
        dist4[gid] = s;
    }
}

// ---------------- kernel 4: mean over 256 partials ----------------
__global__ __launch_bounds__(256) void mean_kernel(const float* __restrict__ dist4,
                                                   float* __restrict__ out) {
    __shared__ float red[4];
    int t = threadIdx.x;
    float v = dist4[t];
    #pragma unroll
    for (int off = 32; off; off >>= 1) v += __shfl_xor(v, off, 64);
    if ((t & 63) == 0) red[t >> 6] = v;
    __syncthreads();
    if (t == 0) out[0] = -SINK_EPS_F * (red[0] + red[1] + red[2] + red[3]) * (1.0f / 64.0f);
}

extern "C" void kernel_launch(void* const* d_in, const int* in_sizes, int n_in,
                              void* d_out, int out_size, void* d_ws, size_t ws_size,
                              hipStream_t stream) {
    const float* src = (const float*)d_in[0];
    const float* tgt = (const float*)d_in[1];
    char* ws = (char*)d_ws;

    float*          inv_ns = (float*)(ws);
    float*          inv_nt = (float*)(ws + 131072);
    unsigned short* W      = (unsigned short*)(ws + 262144);
    float*          Sp     = (float*)(ws + 262144 + 33554432);                       // 1 MB (2 bufs)
    float*          dist4  = (float*)(ws + 262144 + 33554432 + 1048576);
    unsigned int*   bar    = (unsigned int*)(ws + 262144 + 33554432 + 1048576 + 4096);
    float*          out    = (float*)d_out;

    hipMemsetAsync(bar, 0, 64 * sizeof(unsigned int), stream);

    hipLaunchKernelGGL(norm_kernel,     dim3(16384), dim3(256),  0, stream, src, tgt, inv_ns, inv_nt);
    hipLaunchKernelGGL(cost_kernel,     dim3(1024),  dim3(256),  0, stream, src, tgt, inv_ns, inv_nt, W);
    hipLaunchKernelGGL(sinkhorn_kernel, dim3(256),   dim3(1024), 0, stream, W, Sp, bar, dist4);
    hipLaunchKernelGGL(mean_kernel,     dim3(1),     dim3(256),  0, stream, dist4, out);
}